// Round 6
// baseline (158.652 us; speedup 1.0000x reference)
//
#include <hip/hip_runtime.h>
#include <math.h>

// MultiheadSelfAttention2D: C=256, AC=64, HEADS=16, HEAD_DIM=4, L=4096.
// out[d,i] = sum_j exp(q_j.k_i) * (V[d,j]/Z_j), Z_j = sum_m exp(q_j.k_m).
// q,k unit vectors => x = q.k in [-1,1]. exp(x) ~= T5(x), rank-126 exact
// factorization over monomials q^a k^a (deg<=5, 4 vars):
//   S_f = sum_m psi_f(k_m);  Z_j = sum_f (q^a/a!)_f S_f
//   M[f][d] = (1/a!) sum_j q_j^a V[d,j]/Z_j;  out[d,i] = sum_f psi_f(k_i) M[f][d]
//
// R6: dispatch-count round. R5 evidence: ~10us/dispatch overhead dominates
// (9 dispatches, ~30us modeled work, 147us measured). Features are NEVER
// stored now (recomputed, ~160 VALU per use vs HBM round-trip); S-sum is
// folded into qkv via row-shuffles; no atomics -> no memsets. 5 dispatches.

constexpr int SL = 4096;
constexpr int NF = 126;

typedef float f32x4 __attribute__((ext_vector_type(4)));

// inverse factorial by runtime index, select tree (no scratch arrays)
__device__ __forceinline__ float invfact(int e) {
    return e < 2 ? 1.f : e == 2 ? 0.5f : e == 3 ? (1.f / 6.f)
         : e == 4 ? (1.f / 24.f) : (1.f / 120.f);
}

// f -> exponent tuple (a,b,c,d), enumeration order shared by all kernels
__device__ __forceinline__ void f2abcd(int f, int& A, int& B, int& C, int& D) {
    for (int a = 0; a <= 5; ++a)
        for (int b = 0; b <= 5 - a; ++b)
            for (int c = 0; c <= 5 - a - b; ++c)
                for (int d = 0; d <= 5 - a - b - c; ++d)
                    if (f-- == 0) { A = a; B = b; C = c; D = d; return; }
}

__device__ __forceinline__ float powu(float x, int e) {  // e uniform, <=5
    float r = 1.f;
    for (int t = 0; t < e; ++t) r *= x;
    return r;
}

#define FOR_MONOMIALS(BODY)                         \
    {                                               \
        int f = 0;                                  \
        _Pragma("unroll")                           \
        for (int a = 0; a <= 5; ++a)                \
        _Pragma("unroll")                           \
        for (int b = 0; b <= 5 - a; ++b)            \
        _Pragma("unroll")                           \
        for (int c = 0; c <= 5 - a - b; ++c)        \
        _Pragma("unroll")                           \
        for (int d = 0; d <= 5 - a - b - c; ++d) {  \
            BODY;                                   \
            ++f;                                    \
        }                                           \
    }

// ---------------------------------------------------------------------------
// Kernel 1: QKV projection + L2-norm; K-waves also emit psi row-partials
// Sp[h][256][126] (row = lt*4 + lane/16; 4-shuffle row-reduce; the 16 lanes
// of a row store the same value to the same address -> no masking needed).
// Grid (64 l-tiles, 4 a-blocks), block 256.
// ---------------------------------------------------------------------------
__global__ __launch_bounds__(256) void qkv_kernel(
    const float* __restrict__ X,
    const float* __restrict__ Wq, const float* __restrict__ bq,
    const float* __restrict__ Wk, const float* __restrict__ bk,
    const float* __restrict__ Wv, const float* __restrict__ bv,
    float* __restrict__ Qn, float* __restrict__ Kn, float* __restrict__ V4,
    float* __restrict__ Sp)
{
    __shared__ float XL[256 * 64];
    const int tid = threadIdx.x;
    const int lt  = blockIdx.x;
    const int ab  = blockIdx.y;

    const float4* Xg  = (const float4*)X;
    float4*       XL4 = (float4*)XL;
    #pragma unroll
    for (int i = 0; i < 16; ++i) {
        int idx = tid + i * 256;
        int c = idx >> 4, lq = idx & 15;
        XL4[c * 16 + lq] = Xg[c * (SL / 4) + lt * 16 + lq];
    }
    __syncthreads();

    const int lane   = tid & 63;
    const int wv     = __builtin_amdgcn_readfirstlane(tid >> 6);
    const int a_base = ab * 48 + wv * 12;
    const int l      = lt * 64 + lane;

    float acc[12];
    const float* wrow[12];
    #pragma unroll
    for (int k = 0; k < 12; ++k) {
        int a = a_base + k;
        if (a < 64)       { wrow[k] = Wq + a * 256;         acc[k] = bq[a]; }
        else if (a < 128) { wrow[k] = Wk + (a - 64) * 256;  acc[k] = bk[a - 64]; }
        else              { wrow[k] = Wv + (a - 128) * 256; acc[k] = bv[a - 128]; }
    }

    #pragma unroll 4
    for (int c = 0; c < 256; ++c) {
        float x = XL[c * 64 + lane];
        #pragma unroll
        for (int k = 0; k < 12; ++k) acc[k] = fmaf(wrow[k][c], x, acc[k]);
    }

    #pragma unroll
    for (int g = 0; g < 3; ++g) {
        int a0 = a_base + g * 4;
        float y0 = acc[g * 4 + 0], y1 = acc[g * 4 + 1];
        float y2 = acc[g * 4 + 2], y3 = acc[g * 4 + 3];
        int type = a0 >> 6;                 // 0=Q 1=K 2=V (wave-uniform)
        if (type < 2) {
            float n   = sqrtf(y0 * y0 + y1 * y1 + y2 * y2 + y3 * y3);
            float inv = 1.0f / fmaxf(n, 1e-12f);
            y0 *= inv; y1 *= inv; y2 *= inv; y3 *= inv;
        }
        int h = (a0 & 63) >> 2;
        if (type == 0) {
            ((float4*)Qn)[h * SL + l] = make_float4(y0, y1, y2, y3);
        } else if (type == 2) {
            ((float4*)V4)[h * SL + l] = make_float4(y0, y1, y2, y3);
        } else {
            ((float4*)Kn)[h * SL + l] = make_float4(y0, y1, y2, y3);
            // psi row-partials
            float p0[6], p1[6], p2[6], p3[6];
            p0[0] = p1[0] = p2[0] = p3[0] = 1.f;
            #pragma unroll
            for (int i = 1; i < 6; ++i) {
                p0[i] = p0[i - 1] * y0; p1[i] = p1[i - 1] * y1;
                p2[i] = p2[i - 1] * y2; p3[i] = p3[i - 1] * y3;
            }
            float* sp = Sp + ((size_t)h * 256 + lt * 4 + (lane >> 4)) * NF;
            FOR_MONOMIALS({
                float v = (p0[a] * p1[b]) * (p2[c] * p3[d]);
                v += __shfl_xor(v, 1);
                v += __shfl_xor(v, 2);
                v += __shfl_xor(v, 4);
                v += __shfl_xor(v, 8);   // 16-lane row sum, all rows
                sp[f] = v;               // 16 lanes/row: same value, same addr
            })
        }
    }
}

// ---------------------------------------------------------------------------
// Kernel 2: Sf[f] = (1/a!)*sum_u Sp[h][u][f]; Z_j = sum_f q_j^a Sf[f];
// Vz = V/Z. Grid (16 j-tiles, 16 heads), block 256.
// ---------------------------------------------------------------------------
__global__ __launch_bounds__(256) void zvz_kernel(
    const float* __restrict__ Qn, const float* __restrict__ Sp,
    const float* __restrict__ V4, float* __restrict__ Vz)
{
    __shared__ float Sf[NF];
    const int tid = threadIdx.x;
    const int h   = blockIdx.y;

    if (tid < NF) {
        const float* sp = Sp + (size_t)h * 256 * NF + tid;
        float s = 0.f;
        #pragma unroll 8
        for (int u = 0; u < 256; ++u) s += sp[u * NF];
        int A, B, C, D;
        f2abcd(tid, A, B, C, D);
        Sf[tid] = s * ((invfact(A) * invfact(B)) * (invfact(C) * invfact(D)));
    }
    __syncthreads();

    const int j = blockIdx.x * 256 + tid;
    float4 q = ((const float4*)Qn)[h * SL + j];
    float p0[6], p1[6], p2[6], p3[6];
    p0[0] = p1[0] = p2[0] = p3[0] = 1.f;
    #pragma unroll
    for (int i = 1; i < 6; ++i) {
        p0[i] = p0[i - 1] * q.x; p1[i] = p1[i - 1] * q.y;
        p2[i] = p2[i - 1] * q.z; p3[i] = p3[i - 1] * q.w;
    }
    float z = 0.f;
    FOR_MONOMIALS({
        z = fmaf((p0[a] * p1[b]) * (p2[c] * p3[d]), Sf[f], z);
    })
    float inv = 1.0f / z;
    float4 v = ((const float4*)V4)[h * SL + j];
    ((float4*)Vz)[h * SL + j] = make_float4(v.x * inv, v.y * inv, v.z * inv, v.w * inv);
}

// ---------------------------------------------------------------------------
// Kernel 3: M[h][f][d] = (1/a!) sum_j q_j^a Vz[d,j]. 3 features per block.
// Grid (42, 16), block 256 (4 waves).
// ---------------------------------------------------------------------------
__global__ __launch_bounds__(256) void mmat_kernel(
    const float* __restrict__ Qn, const float* __restrict__ Vz,
    float* __restrict__ Mm)
{
    const int tid = threadIdx.x;
    const int h   = blockIdx.y;
    const int g3  = blockIdx.x * 3;

    int A[3], B[3], C[3], D[3];
    #pragma unroll
    for (int fi = 0; fi < 3; ++fi) f2abcd(g3 + fi, A[fi], B[fi], C[fi], D[fi]);

    float acc[12];
    #pragma unroll
    for (int k = 0; k < 12; ++k) acc[k] = 0.f;

    for (int u = 0; u < 16; ++u) {
        int j = tid + u * 256;
        float4 q = ((const float4*)Qn)[h * SL + j];
        float4 v = ((const float4*)Vz)[h * SL + j];
        #pragma unroll
        for (int fi = 0; fi < 3; ++fi) {
            float m = (powu(q.x, A[fi]) * powu(q.y, B[fi])) *
                      (powu(q.z, C[fi]) * powu(q.w, D[fi]));
            acc[fi * 4 + 0] = fmaf(m, v.x, acc[fi * 4 + 0]);
            acc[fi * 4 + 1] = fmaf(m, v.y, acc[fi * 4 + 1]);
            acc[fi * 4 + 2] = fmaf(m, v.z, acc[fi * 4 + 2]);
            acc[fi * 4 + 3] = fmaf(m, v.w, acc[fi * 4 + 3]);
        }
    }
    #pragma unroll
    for (int off = 32; off; off >>= 1)
        #pragma unroll
        for (int k = 0; k < 12; ++k) acc[k] += __shfl_down(acc[k], off);

    __shared__ float red[4][12];
    const int lane = tid & 63, wv = tid >> 6;
    if (lane == 0) {
        #pragma unroll
        for (int k = 0; k < 12; ++k) red[wv][k] = acc[k];
    }
    __syncthreads();
    if (tid < 12) {
        int fi = tid >> 2, dd = tid & 3;
        float s = (red[0][tid] + red[1][tid]) + (red[2][tid] + red[3][tid]);
        s *= (invfact(A[fi]) * invfact(B[fi])) * (invfact(C[fi]) * invfact(D[fi]));
        Mm[(size_t)(h * NF + g3 + fi) * 4 + dd] = s;
    }
}

// ---------------------------------------------------------------------------
// Kernel 4: AO[h*4+d][i] = sum_f psi_f(k_i) * M[f][d]. Plain stores.
// Grid (16 i-tiles, 16 heads), block 256.
// ---------------------------------------------------------------------------
__global__ __launch_bounds__(256) void out_kernel(
    const float* __restrict__ Kn, const float* __restrict__ Mm,
    float* __restrict__ AO)
{
    const int i = blockIdx.x * 256 + threadIdx.x;
    const int h = blockIdx.y;
    float4 k = ((const float4*)Kn)[h * SL + i];
    float p0[6], p1[6], p2[6], p3[6];
    p0[0] = p1[0] = p2[0] = p3[0] = 1.f;
    #pragma unroll
    for (int t = 1; t < 6; ++t) {
        p0[t] = p0[t - 1] * k.x; p1[t] = p1[t - 1] * k.y;
        p2[t] = p2[t - 1] * k.z; p3[t] = p3[t - 1] * k.w;
    }
    const float4* Mh = (const float4*)Mm + h * NF;
    float a0 = 0.f, a1 = 0.f, a2 = 0.f, a3 = 0.f;
    FOR_MONOMIALS({
        float m = (p0[a] * p1[b]) * (p2[c] * p3[d]);
        float4 mm = Mh[f];
        a0 = fmaf(m, mm.x, a0); a1 = fmaf(m, mm.y, a1);
        a2 = fmaf(m, mm.z, a2); a3 = fmaf(m, mm.w, a3);
    })
    AO[(h * 4 + 0) * SL + i] = a0;
    AO[(h * 4 + 1) * SL + i] = a1;
    AO[(h * 4 + 2) * SL + i] = a2;
    AO[(h * 4 + 3) * SL + i] = a3;
}

// ---------------------------------------------------------------------------
// Kernel 5: output projection + bias + residual.
// ---------------------------------------------------------------------------
__global__ __launch_bounds__(256) void oproj_kernel(
    const float* __restrict__ AO, const float* __restrict__ Wo,
    const float* __restrict__ bo, const float* __restrict__ X,
    float* __restrict__ Y)
{
    const int lane = threadIdx.x & 63;
    const int wv   = __builtin_amdgcn_readfirstlane(threadIdx.x >> 6);
    const int l    = blockIdx.x * 64 + lane;
    const int cb   = blockIdx.y * 16 + wv * 4;

    float a0 = bo[cb + 0], a1 = bo[cb + 1], a2 = bo[cb + 2], a3 = bo[cb + 3];
    #pragma unroll 16
    for (int o = 0; o < 64; ++o) {
        float x = AO[o * SL + l];
        a0 = fmaf(Wo[(cb + 0) * 64 + o], x, a0);
        a1 = fmaf(Wo[(cb + 1) * 64 + o], x, a1);
        a2 = fmaf(Wo[(cb + 2) * 64 + o], x, a2);
        a3 = fmaf(Wo[(cb + 3) * 64 + o], x, a3);
    }
    Y[(cb + 0) * SL + l] = a0 + X[(cb + 0) * SL + l];
    Y[(cb + 1) * SL + l] = a1 + X[(cb + 1) * SL + l];
    Y[(cb + 2) * SL + l] = a2 + X[(cb + 2) * SL + l];
    Y[(cb + 3) * SL + l] = a3 + X[(cb + 3) * SL + l];
}

// ---------------------------------------------------------------------------
extern "C" void kernel_launch(void* const* d_in, const int* in_sizes, int n_in,
                              void* d_out, int out_size, void* d_ws, size_t ws_size,
                              hipStream_t stream)
{
    const float* X  = (const float*)d_in[0];
    const float* Wq = (const float*)d_in[1];
    const float* bq = (const float*)d_in[2];
    const float* Wk = (const float*)d_in[3];
    const float* bk = (const float*)d_in[4];
    const float* Wv = (const float*)d_in[5];
    const float* bv = (const float*)d_in[6];
    const float* Wo = (const float*)d_in[7];
    const float* bo = (const float*)d_in[8];
    float* Y = (float*)d_out;

    // workspace (~8 MB), all fully written before read (no memsets needed)
    char* w = (char*)d_ws;
    float* Qn = (float*)(w + (0 << 20));   // [16][SL][4]      1 MB
    float* Kn = (float*)(w + (1 << 20));   // [16][SL][4]      1 MB
    float* V4 = (float*)(w + (2 << 20));   // [16][SL][4]      1 MB
    float* Vz = (float*)(w + (3 << 20));   // [16][SL][4]      1 MB
    float* AO = (float*)(w + (4 << 20));   // [64][SL]         1 MB
    float* Mm = (float*)(w + (5 << 20));   // [16][126][4]     32 KB
    float* Sp = (float*)(w + (6 << 20));   // [16][256][126]   ~2 MB

    qkv_kernel<<<dim3(64, 4), 256, 0, stream>>>(X, Wq, bq, Wk, bk, Wv, bv,
                                                Qn, Kn, V4, Sp);
    zvz_kernel<<<dim3(16, 16), 256, 0, stream>>>(Qn, Sp, V4, Vz);
    mmat_kernel<<<dim3(42, 16), 256, 0, stream>>>(Qn, Vz, Mm);
    out_kernel<<<dim3(16, 16), 256, 0, stream>>>(Kn, Mm, AO);
    oproj_kernel<<<dim3(64, 16), 256, 0, stream>>>(AO, Wo, bo, X, Y);
}